// Round 2
// baseline (86.231 us; speedup 1.0000x reference)
//
#include <hip/hip_runtime.h>
#include <math.h>

// ApproxCompressor, single-pass fused kernel.
//
// Math: h[k] = (1-a)a^k FIR (K=16384) == one-pole IIR y[l] = a*y[l-1] + (1-a)*e[l]
// exactly, since a^16384 <= e^-580 == 0 in fp32 for a = sigmoid(N(0,1)) draws.
//
// Structure: decoupled lookback over 64 chunks of 2048 per batch.
//   - per block: load chunk (float4), per-thread 8-elem scan, Hillis-Steele
//     affine-map wave scan + LDS cross-wave combine -> per-thread prefix AND
//     block-local final F (zero carry-in).
//   - publish F with agent-scope release atomic (flag in high 32 bits).
//   - wave-0 lookback: carry(c) = sum_l a_cl^l * F(c-1-l), a_cl = a^2048.
//     Lanes whose weight underflows to 0 (the common case: a_cl <= e^-73)
//     skip the flag wait entirely -> spin time ~ skew of adjacent blocks.
//   - exact envelope walk, quadratic-knee gain, gain * x, float4 store.
//
// Deadlock safety: __launch_bounds__(256,8) -> <=64 VGPR -> 8 blocks/CU ->
// all 2048 blocks co-resident; every block publishes before it waits.
// Flags pre-zeroed by a hipMemsetAsync node each call (graph-capturable).

namespace {

constexpr int N_BATCH = 32;
constexpr int L_LEN   = 131072;
constexpr int NCHUNK  = 64;
constexpr int CL      = L_LEN / NCHUNK;   // 2048
constexpr int NTHR    = 256;
constexpr int SEG     = CL / NTHR;        // 8
constexpr int NWAVE   = NTHR / 64;        // 4
constexpr float EPS_F = 1e-5f;

__device__ __forceinline__ void batch_alpha(float z, float& alpha, float& oma, float& la) {
    if (z >= 0.f) {
        float e = expf(-z);
        float d = 1.f + e;
        alpha = 1.f / d;
        oma   = e / d;
        la    = -log1pf(e);
    } else {
        float e = expf(z);
        float d = 1.f + e;
        alpha = e / d;
        oma   = 1.f / d;
        la    = z - log1pf(e);
    }
}

__global__ __launch_bounds__(NTHR, 8) void k_fused(
    const float* __restrict__ x,
    const float* __restrict__ z_alpha,
    const float* __restrict__ log_threshold,
    const float* __restrict__ log_ratio,
    const float* __restrict__ log_knee,
    unsigned long long* __restrict__ slots,   // (N, NCHUNK), pre-zeroed flag|value
    float* __restrict__ out)
{
    const int chunk = blockIdx.x;
    const int n     = blockIdx.y;
    const int t     = threadIdx.x;
    const int lane  = t & 63;
    const int wv    = t >> 6;

    float alpha, oma, la;
    batch_alpha(z_alpha[n], alpha, oma, la);
    const float h_oma = 0.5f * oma;

    const size_t base = (size_t)n * 2 * L_LEN + (size_t)chunk * CL + (size_t)t * SEG;
    const float* x0 = x + base;
    const float* x1 = x0 + L_LEN;

    float4 a0 = *reinterpret_cast<const float4*>(x0);
    float4 a1 = *reinterpret_cast<const float4*>(x0 + 4);
    float4 b0 = *reinterpret_cast<const float4*>(x1);
    float4 b1 = *reinterpret_cast<const float4*>(x1 + 4);

    // walk 1: per-thread local final with zero carry-in (e recomputed in walk 2)
    float f = 0.f;
    f = fmaf(alpha, f, h_oma * fmaf(a0.x, a0.x, b0.x * b0.x));
    f = fmaf(alpha, f, h_oma * fmaf(a0.y, a0.y, b0.y * b0.y));
    f = fmaf(alpha, f, h_oma * fmaf(a0.z, a0.z, b0.z * b0.z));
    f = fmaf(alpha, f, h_oma * fmaf(a0.w, a0.w, b0.w * b0.w));
    f = fmaf(alpha, f, h_oma * fmaf(a1.x, a1.x, b1.x * b1.x));
    f = fmaf(alpha, f, h_oma * fmaf(a1.y, a1.y, b1.y * b1.y));
    f = fmaf(alpha, f, h_oma * fmaf(a1.z, a1.z, b1.z * b1.z));
    f = fmaf(alpha, f, h_oma * fmaf(a1.w, a1.w, b1.w * b1.w));

    // in-wave Hillis-Steele inclusive scan of affine maps (A, b): y -> A*y + b
    float A = expf((float)SEG * la);   // alpha^SEG
    float b = f;
    #pragma unroll
    for (int d = 1; d < 64; d <<= 1) {
        float Ap = __shfl_up(A, d);
        float bp = __shfl_up(b, d);
        if (lane >= d) {
            b = fmaf(A, bp, b);   // pre-update A!
            A *= Ap;
        }
    }

    __shared__ float wA[NWAVE], wB[NWAVE];
    __shared__ float sCarry;
    if (lane == 63) { wA[wv] = A; wB[wv] = b; }
    __syncthreads();

    // block-local final (zero carry-in) and publish
    if (t == 0) {
        float F = 0.f;
        #pragma unroll
        for (int k = 0; k < NWAVE; ++k) F = fmaf(wA[k], F, wB[k]);
        unsigned long long pk = (1ull << 32) | (unsigned long long)__float_as_uint(F);
        __hip_atomic_store(&slots[n * NCHUNK + chunk], pk,
                           __ATOMIC_RELEASE, __HIP_MEMORY_SCOPE_AGENT);
    }

    // lookback: carry = sum_l a_cl^l * F(chunk-1-l); skip lanes with weight == 0
    if (wv == 0) {
        const float cl_la = (float)CL * la;
        float contrib = 0.f;
        if (lane < chunk) {
            float w = expf((float)lane * cl_la);   // a_cl^lane, underflows fast
            if (w > 0.f) {
                const unsigned long long* sp = &slots[n * NCHUNK + (chunk - 1 - lane)];
                unsigned long long v = __hip_atomic_load(sp, __ATOMIC_ACQUIRE,
                                                         __HIP_MEMORY_SCOPE_AGENT);
                while (!(v >> 32)) {
                    __builtin_amdgcn_s_sleep(1);
                    v = __hip_atomic_load(sp, __ATOMIC_ACQUIRE,
                                          __HIP_MEMORY_SCOPE_AGENT);
                }
                contrib = w * __uint_as_float((unsigned int)v);
            }
        }
        #pragma unroll
        for (int d = 32; d > 0; d >>= 1) contrib += __shfl_down(contrib, d);
        if (lane == 0) sCarry = contrib;
    }
    __syncthreads();

    // per-thread carry-in: exclusive prefix applied to chunk carry
    float PA = 1.f, PB = 0.f;
    #pragma unroll
    for (int k = 0; k < NWAVE - 1; ++k) {
        if (k < wv) {
            PB = fmaf(wA[k], PB, wB[k]);
            PA *= wA[k];
        }
    }
    float EA = __shfl_up(A, 1);
    float EB = __shfl_up(b, 1);
    if (lane == 0) { EA = 1.f; EB = 0.f; }
    float y = fmaf(EA, fmaf(PA, sCarry, PB), EB);

    // gain params
    const float T     = log_threshold[n] - 6.0f;
    const float R     = 1.0f + expf(log_ratio[n]);
    const float c     = 1.0f / R - 1.0f;
    const float W     = expf(log_knee[n]);
    const float inv4W = 1.0f / (4.0f * W);

    // walk 2: exact envelope -> knee gain
    float gn[SEG];
    float e[SEG];
    e[0] = fmaf(a0.x, a0.x, b0.x * b0.x);
    e[1] = fmaf(a0.y, a0.y, b0.y * b0.y);
    e[2] = fmaf(a0.z, a0.z, b0.z * b0.z);
    e[3] = fmaf(a0.w, a0.w, b0.w * b0.w);
    e[4] = fmaf(a1.x, a1.x, b1.x * b1.x);
    e[5] = fmaf(a1.y, a1.y, b1.y * b1.y);
    e[6] = fmaf(a1.z, a1.z, b1.z * b1.z);
    e[7] = fmaf(a1.w, a1.w, b1.w * b1.w);
    #pragma unroll
    for (int i = 0; i < SEG; ++i) {
        y = fmaf(alpha, y, h_oma * e[i]);
        float le = logf(y + EPS_F);
        float g;
        if (le >= T + W) {
            g = c * (le - T);
        } else if (le < T - W) {
            g = 0.f;
        } else {
            float u = le - T + W;
            g = c * u * u * inv4W;
        }
        gn[i] = expf(g);
    }

    float* o0 = out + base;
    float* o1 = o0 + L_LEN;
    *reinterpret_cast<float4*>(o0)     = make_float4(gn[0]*a0.x, gn[1]*a0.y, gn[2]*a0.z, gn[3]*a0.w);
    *reinterpret_cast<float4*>(o0 + 4) = make_float4(gn[4]*a1.x, gn[5]*a1.y, gn[6]*a1.z, gn[7]*a1.w);
    *reinterpret_cast<float4*>(o1)     = make_float4(gn[0]*b0.x, gn[1]*b0.y, gn[2]*b0.z, gn[3]*b0.w);
    *reinterpret_cast<float4*>(o1 + 4) = make_float4(gn[4]*b1.x, gn[5]*b1.y, gn[6]*b1.z, gn[7]*b1.w);
}

} // namespace

extern "C" void kernel_launch(void* const* d_in, const int* in_sizes, int n_in,
                              void* d_out, int out_size, void* d_ws, size_t ws_size,
                              hipStream_t stream) {
    const float* x  = (const float*)d_in[0];   // input_signals (32, 2, 131072)
    const float* za = (const float*)d_in[1];   // z_alpha
    const float* lt = (const float*)d_in[2];   // log_threshold
    const float* lr = (const float*)d_in[3];   // log_ratio
    const float* lk = (const float*)d_in[4];   // log_knee
    float* out = (float*)d_out;

    unsigned long long* slots = (unsigned long long*)d_ws;   // 32*64*8 = 16 KB

    hipMemsetAsync(slots, 0, (size_t)N_BATCH * NCHUNK * sizeof(unsigned long long),
                   stream);

    dim3 grid(NCHUNK, N_BATCH);   // 2048 blocks, fully co-resident at 8/CU
    k_fused<<<grid, NTHR, 0, stream>>>(x, za, lt, lr, lk, slots, out);
}

// Round 3
// 19.377 us; speedup vs baseline: 4.4501x; 4.4501x over previous
//
#include <hip/hip_runtime.h>
#include <math.h>

// ApproxCompressor, single-kernel, zero-synchronization version.
//
// Math: h[k] = (1-a)a^k FIR (K=16384) == one-pole IIR exactly in fp32
// (a^16384 <= e^-580 == 0 for a = sigmoid(N(0,1))).
//
// Round-2 post-mortem: decoupled-lookback spin with agent-scope atomics
// caused an L2 coherence storm (VALUBusy 9%, HBM 6%, 86 us). Fix: no
// cross-block communication at all. Each block (chunk c, batch n)
// recomputes its carry-in redundantly from the PREVIOUS chunk's raw data:
//   carry(c) = sum_j (1-a) a^{CL-1-j} e_prev[j]      (+ a^CL*carry(c-1),
// dropped: <= e^-73 ~ 1e-32 for any plausible alpha). Threads whose scale
// a^{SEG*(255-t)} underflows to 0 in fp32 skip the prev load entirely, so
// for typical alpha only ~128 trailing samples are re-read, and they hit
// L3 (input 33.5 MB << 256 MB L3) / same-XCD L2 via the swizzle below.

namespace {

constexpr int N_BATCH = 32;
constexpr int L_LEN   = 131072;
constexpr int NCHUNK  = 64;
constexpr int CL      = L_LEN / NCHUNK;   // 2048
constexpr int NTHR    = 256;
constexpr int SEG     = CL / NTHR;        // 8
constexpr int NWAVE   = NTHR / 64;        // 4
constexpr int NBLK    = NCHUNK * N_BATCH; // 2048
constexpr int NXCD    = 8;
constexpr float EPS_F = 1e-5f;

__device__ __forceinline__ void batch_alpha(float z, float& alpha, float& oma, float& la) {
    // alpha = sigmoid(z), oma = 1-alpha, la = log(alpha), numerically stable
    if (z >= 0.f) {
        float e = expf(-z);
        float d = 1.f + e;
        alpha = 1.f / d;
        oma   = e / d;
        la    = -log1pf(e);
    } else {
        float e = expf(z);
        float d = 1.f + e;
        alpha = e / d;
        oma   = 1.f / d;
        la    = z - log1pf(e);
    }
}

__global__ __launch_bounds__(NTHR) void k_compress(
    const float* __restrict__ x,
    const float* __restrict__ z_alpha,
    const float* __restrict__ log_threshold,
    const float* __restrict__ log_ratio,
    const float* __restrict__ log_knee,
    float* __restrict__ out)
{
    // XCD-aware swizzle: consecutive work items (= consecutive chunks of one
    // batch) land on the same XCD, so the prev-chunk re-read hits local L2.
    const int bid  = blockIdx.x;               // 0..2047
    const int work = (bid & (NXCD - 1)) * (NBLK / NXCD) + (bid >> 3);
    const int n    = work >> 6;                // /NCHUNK
    const int c    = work & (NCHUNK - 1);
    const int t    = threadIdx.x;
    const int lane = t & 63;
    const int wv   = t >> 6;

    float alpha, oma, la;
    batch_alpha(z_alpha[n], alpha, oma, la);
    const float h_oma = 0.5f * oma;

    const size_t base = (size_t)n * 2 * L_LEN + (size_t)c * CL + (size_t)t * SEG;
    const float* x0 = x + base;
    const float* x1 = x0 + L_LEN;

    __shared__ float part[NWAVE];
    __shared__ float wA[NWAVE], wB[NWAVE];

    // ---- carry from previous chunk (redundant recompute, no sync) ----
    if (c > 0) {
        // thread t's contribution scale: alpha^(SEG*(NTHR-1-t)); if it
        // underflows to 0 in fp32 the whole contribution is exactly 0.
        float w_t = expf((float)(SEG * (NTHR - 1 - t)) * la);
        float v = 0.f;
        if (w_t > 0.f) {
            const float* p0 = x0 - CL;
            const float* p1 = p0 + L_LEN;
            float4 pa0 = *reinterpret_cast<const float4*>(p0);
            float4 pa1 = *reinterpret_cast<const float4*>(p0 + 4);
            float4 pb0 = *reinterpret_cast<const float4*>(p1);
            float4 pb1 = *reinterpret_cast<const float4*>(p1 + 4);
            float yl = 0.f;
            yl = fmaf(alpha, yl, h_oma * fmaf(pa0.x, pa0.x, pb0.x * pb0.x));
            yl = fmaf(alpha, yl, h_oma * fmaf(pa0.y, pa0.y, pb0.y * pb0.y));
            yl = fmaf(alpha, yl, h_oma * fmaf(pa0.z, pa0.z, pb0.z * pb0.z));
            yl = fmaf(alpha, yl, h_oma * fmaf(pa0.w, pa0.w, pb0.w * pb0.w));
            yl = fmaf(alpha, yl, h_oma * fmaf(pa1.x, pa1.x, pb1.x * pb1.x));
            yl = fmaf(alpha, yl, h_oma * fmaf(pa1.y, pa1.y, pb1.y * pb1.y));
            yl = fmaf(alpha, yl, h_oma * fmaf(pa1.z, pa1.z, pb1.z * pb1.z));
            yl = fmaf(alpha, yl, h_oma * fmaf(pa1.w, pa1.w, pb1.w * pb1.w));
            v = w_t * yl;
        }
        #pragma unroll
        for (int d = 32; d > 0; d >>= 1) v += __shfl_down(v, d);
        if (lane == 0) part[wv] = v;
    }

    // ---- own chunk: load + per-thread local scan ----
    float4 a0 = *reinterpret_cast<const float4*>(x0);
    float4 a1 = *reinterpret_cast<const float4*>(x0 + 4);
    float4 b0 = *reinterpret_cast<const float4*>(x1);
    float4 b1 = *reinterpret_cast<const float4*>(x1 + 4);

    float f = 0.f;
    f = fmaf(alpha, f, h_oma * fmaf(a0.x, a0.x, b0.x * b0.x));
    f = fmaf(alpha, f, h_oma * fmaf(a0.y, a0.y, b0.y * b0.y));
    f = fmaf(alpha, f, h_oma * fmaf(a0.z, a0.z, b0.z * b0.z));
    f = fmaf(alpha, f, h_oma * fmaf(a0.w, a0.w, b0.w * b0.w));
    f = fmaf(alpha, f, h_oma * fmaf(a1.x, a1.x, b1.x * b1.x));
    f = fmaf(alpha, f, h_oma * fmaf(a1.y, a1.y, b1.y * b1.y));
    f = fmaf(alpha, f, h_oma * fmaf(a1.z, a1.z, b1.z * b1.z));
    f = fmaf(alpha, f, h_oma * fmaf(a1.w, a1.w, b1.w * b1.w));

    // in-wave Hillis-Steele inclusive scan of affine maps (A, b): y -> A*y + b
    float A = expf((float)SEG * la);   // alpha^SEG
    float b = f;
    #pragma unroll
    for (int d = 1; d < 64; d <<= 1) {
        float Ap = __shfl_up(A, d);
        float bp = __shfl_up(b, d);
        if (lane >= d) {
            b = fmaf(A, bp, b);   // pre-update A!
            A *= Ap;
        }
    }
    if (lane == 63) { wA[wv] = A; wB[wv] = b; }

    __syncthreads();   // publishes part[] and wA/wB[]

    float carry = 0.f;
    if (c > 0) {
        #pragma unroll
        for (int k = 0; k < NWAVE; ++k) carry += part[k];
    }

    // exclusive prefix for this thread: waves 0..wv-1 composed, then lane-1
    float PA = 1.f, PB = 0.f;
    #pragma unroll
    for (int k = 0; k < NWAVE - 1; ++k) {
        if (k < wv) {
            PB = fmaf(wA[k], PB, wB[k]);
            PA *= wA[k];
        }
    }
    float EA = __shfl_up(A, 1);
    float EB = __shfl_up(b, 1);
    if (lane == 0) { EA = 1.f; EB = 0.f; }
    float y = fmaf(EA, fmaf(PA, carry, PB), EB);   // env entering this segment

    // ---- gain params ----
    const float T     = log_threshold[n] - 6.0f;
    const float R     = 1.0f + expf(log_ratio[n]);
    const float cc    = 1.0f / R - 1.0f;
    const float W     = expf(log_knee[n]);
    const float inv4W = 1.0f / (4.0f * W);

    // ---- walk 2: exact envelope -> quadratic-knee gain ----
    float e[SEG];
    e[0] = fmaf(a0.x, a0.x, b0.x * b0.x);
    e[1] = fmaf(a0.y, a0.y, b0.y * b0.y);
    e[2] = fmaf(a0.z, a0.z, b0.z * b0.z);
    e[3] = fmaf(a0.w, a0.w, b0.w * b0.w);
    e[4] = fmaf(a1.x, a1.x, b1.x * b1.x);
    e[5] = fmaf(a1.y, a1.y, b1.y * b1.y);
    e[6] = fmaf(a1.z, a1.z, b1.z * b1.z);
    e[7] = fmaf(a1.w, a1.w, b1.w * b1.w);

    float gn[SEG];
    #pragma unroll
    for (int i = 0; i < SEG; ++i) {
        y = fmaf(alpha, y, h_oma * e[i]);
        float le = logf(y + EPS_F);
        float g;
        if (le >= T + W) {
            g = cc * (le - T);
        } else if (le < T - W) {
            g = 0.f;
        } else {
            float u = le - T + W;
            g = cc * u * u * inv4W;
        }
        gn[i] = expf(g);
    }

    float* o0 = out + base;
    float* o1 = o0 + L_LEN;
    *reinterpret_cast<float4*>(o0)     = make_float4(gn[0]*a0.x, gn[1]*a0.y, gn[2]*a0.z, gn[3]*a0.w);
    *reinterpret_cast<float4*>(o0 + 4) = make_float4(gn[4]*a1.x, gn[5]*a1.y, gn[6]*a1.z, gn[7]*a1.w);
    *reinterpret_cast<float4*>(o1)     = make_float4(gn[0]*b0.x, gn[1]*b0.y, gn[2]*b0.z, gn[3]*b0.w);
    *reinterpret_cast<float4*>(o1 + 4) = make_float4(gn[4]*b1.x, gn[5]*b1.y, gn[6]*b1.z, gn[7]*b1.w);
}

} // namespace

extern "C" void kernel_launch(void* const* d_in, const int* in_sizes, int n_in,
                              void* d_out, int out_size, void* d_ws, size_t ws_size,
                              hipStream_t stream) {
    const float* x  = (const float*)d_in[0];   // input_signals (32, 2, 131072)
    const float* za = (const float*)d_in[1];   // z_alpha
    const float* lt = (const float*)d_in[2];   // log_threshold
    const float* lr = (const float*)d_in[3];   // log_ratio
    const float* lk = (const float*)d_in[4];   // log_knee
    float* out = (float*)d_out;

    k_compress<<<NBLK, NTHR, 0, stream>>>(x, za, lt, lr, lk, out);
}